// Round 6
// baseline (215.000 us; speedup 1.0000x reference)
//
#include <hip/hip_runtime.h>

// ---------------------------------------------------------------------------
// CrossAttention (B=1, N=4096, H=8, DH=64, DQ=320, DC=768, L=77, C=4)
// 4 launches: L0{WqT/WoT transpose + ctx K/V GEMM fully-inline}
//             L1{q-GEMM w/ inline x-cvt + folded sim_c0 max}
//             L2{attention, no K/V staging (L2-resident), Ps-only LDS}
//             L3{out = att @ Wo + bo}
// bf16 MFMA 16x16x32, fp32 softmax. ~10us/launch overhead measured R2->R4.
// ---------------------------------------------------------------------------

typedef __attribute__((ext_vector_type(8))) short          bf16x8;
typedef __attribute__((ext_vector_type(4))) float          f32x4;
typedef __attribute__((ext_vector_type(8))) unsigned short u16x8;

// ws byte offsets
#define OFF_WQT  0ull          // 512*320*2    =   327,680
#define OFF_WOT  327680ull     // 320*512*2    =   327,680
#define OFF_QB   655360ull     // 16*4096*64*2 = 8,388,608
#define OFF_KB   9043968ull    // 5*8*80*64*2  =   409,600
#define OFF_VTB  9453568ull    // 5*8*64*96*2  =   983,040
#define OFF_ATT0 10436608ull   // 4096*512*2   = 4,194,304
#define OFF_ATTC 14630912ull   // 4*4096*512*2 = 16,777,216
#define OFF_MAX  31408128ull   // 4 bytes

#define SMEM_BYTES 22016

struct Params {
  const float *x, *uc, *ck, *cv, *ex, *Wq, *Wk, *Wv, *Wo, *bo;
  const int* tp;
  unsigned short *WqT, *WoT, *qb, *kb, *vtb, *att0, *attc;
  unsigned* maxslot;
  float* out;
};

__device__ __forceinline__ unsigned short bf_cvt(float f) {
  unsigned u = __float_as_uint(f);
  unsigned r = u + 0x7FFFu + ((u >> 16) & 1u);
  return (unsigned short)(r >> 16);
}
__device__ __forceinline__ float bf2f(unsigned short u) {
  return __uint_as_float(((unsigned)u) << 16);
}
__device__ __forceinline__ unsigned enc_f(float f) {
  int b = __float_as_int(f);
  return (b >= 0) ? ((unsigned)b | 0x80000000u) : ~(unsigned)b;
}
__device__ __forceinline__ float dec_f(unsigned u) {
  unsigned b = (u & 0x80000000u) ? (u ^ 0x80000000u) : ~u;
  return __int_as_float((int)b);
}
__device__ __forceinline__ f32x4 mfma16(bf16x8 a, bf16x8 b, f32x4 c) {
  return __builtin_amdgcn_mfma_f32_16x16x32_bf16(a, b, c, 0, 0, 0);
}
__device__ __forceinline__ void gload16(const void* g, void* l) {
  __builtin_amdgcn_global_load_lds((const __attribute__((address_space(1))) void*)g,
                                   (__attribute__((address_space(3))) void*)l, 16, 0, 0);
}

__global__ void __launch_bounds__(256, 4) k_all(Params p, int ph) {
  __shared__ __align__(16) char smem_raw[SMEM_BYTES];
  unsigned short* smem = reinterpret_cast<unsigned short*>(smem_raw);
  const int tid  = threadIdx.x;
  const int lane = tid & 63, w = tid >> 6;
  const int l15  = lane & 15, qd = lane >> 4;
  const int v = blockIdx.x;

  // ========== L0: WqT/WoT transpose + ctx K/V GEMM (fully inline) ==========
  if (ph == 0) {
    if (v < 320) {
      if (v == 0 && tid == 0) *p.maxslot = 0u;
      int z = (v >= 160);
      int q = z ? v - 160 : v;
      const float* src = z ? p.Wo : p.Wq;
      unsigned short* dst = z ? p.WoT : p.WqT;
      int R = z ? 512 : 320, C = z ? 320 : 512;
      int rt = z ? (q / 10) : (q / 16), ct = z ? (q % 10) : (q % 16);
      float* T = reinterpret_cast<float*>(smem_raw);  // [32][33]
      int r0 = rt * 32, c0 = ct * 32;
      { int r = tid >> 3, c4 = (tid & 7) * 4;
        float4 t = *reinterpret_cast<const float4*>(src + (size_t)(r0 + r) * C + c0 + c4);
        T[r * 33 + c4] = t.x; T[r * 33 + c4 + 1] = t.y;
        T[r * 33 + c4 + 2] = t.z; T[r * 33 + c4 + 3] = t.w; }
      __syncthreads();
      { int c = tid >> 3, r4 = (tid & 7) * 4;
        ushort4 o = {bf_cvt(T[r4 * 33 + c]), bf_cvt(T[(r4 + 1) * 33 + c]),
                     bf_cvt(T[(r4 + 2) * 33 + c]), bf_cvt(T[(r4 + 3) * 33 + c])};
        *reinterpret_cast<ushort4*>(dst + (size_t)(c0 + c) * R + r0 + r4) = o; }
    } else {
      // ctx K/V GEMM: M=77(pad80) N=512 K=768, BN=64 BK=64, inline cvt+transpose
      int u2 = v - 320;
      int g = u2 >> 3, nb = (u2 & 7) * 64;
      int kv = g >= 5, cidx = g % 5;
      const float* csrc = (cidx == 0) ? p.uc
                        : ((kv ? p.cv : p.ck) + (size_t)(cidx - 1) * 77 * 768);
      const float* wsrc = kv ? p.Wv : p.Wk;
      unsigned short* As = smem;           // [80][68] bf16
      unsigned short* Bs = smem + 80 * 68; // [64][72] bf16 (transposed W)
      f32x4 acc[5] = {};
      for (int k0 = 0; k0 < 768; k0 += 64) {
        for (int u = tid; u < 1280; u += 256) {  // A: ctx[77][64] -> [80][68]
          int r = u >> 4, k4 = (u & 15) * 4;
          ushort4 o = {0, 0, 0, 0};
          if (r < 77) {
            float4 t = *reinterpret_cast<const float4*>(csrc + (size_t)r * 768 + k0 + k4);
            o.x = bf_cvt(t.x); o.y = bf_cvt(t.y); o.z = bf_cvt(t.z); o.w = bf_cvt(t.w);
          }
          *reinterpret_cast<ushort4*>(&As[r * 68 + k4]) = o;
        }
        for (int u = tid; u < 1024; u += 256) {  // B: W[64k][64n] -> [64n][72k]
          int k = u >> 4, n4 = (u & 15) * 4;
          float4 t = *reinterpret_cast<const float4*>(wsrc + (size_t)(k0 + k) * 512 + nb + n4);
          Bs[(n4 + 0) * 72 + k] = bf_cvt(t.x);
          Bs[(n4 + 1) * 72 + k] = bf_cvt(t.y);
          Bs[(n4 + 2) * 72 + k] = bf_cvt(t.z);
          Bs[(n4 + 3) * 72 + k] = bf_cvt(t.w);
        }
        __syncthreads();
#pragma unroll
        for (int ks = 0; ks < 2; ++ks) {
          bf16x8 b = *reinterpret_cast<const bf16x8*>(&Bs[(w * 16 + l15) * 72 + qd * 8 + ks * 32]);
#pragma unroll
          for (int mi = 0; mi < 5; ++mi) {
            bf16x8 a = *reinterpret_cast<const bf16x8*>(&As[(mi * 16 + l15) * 68 + qd * 8 + ks * 32]);
            acc[mi] = mfma16(a, b, acc[mi]);
          }
        }
        __syncthreads();
      }
#pragma unroll
      for (int mi = 0; mi < 5; ++mi)
#pragma unroll
        for (int r = 0; r < 4; ++r) {
          int j = mi * 16 + qd * 4 + r;
          int n = nb + w * 16 + l15, h = n >> 6, d = n & 63;
          unsigned short val = (j < 77) ? bf_cvt(acc[mi][r]) : (unsigned short)0;
          if (kv) p.vtb[((size_t)(cidx * 8 + h) * 64 + d) * 96 + j] = val;
          else    p.kb [((size_t)(cidx * 8 + h) * 80 + j) * 64 + d] = val;
        }
      if (kv) {  // zero vtb cols 80..95 for this block's (h,d) range
        for (int u = tid; u < 1024; u += 256) {
          int dl = u >> 4, j = 80 + (u & 15);
          int n = nb + dl, h = n >> 6, d = n & 63;
          p.vtb[((size_t)(cidx * 8 + h) * 64 + d) * 96 + j] = 0;
        }
      }
    }
  }

  // ========== L1: q = x @ Wq (inline x-cvt) + folded sim_c0 max ============
  else if (ph == 1) {
    int mb = v >> 3, nb_i = v & 7;
    int mb128 = mb * 128, nb = nb_i * 64;
    unsigned short* As = smem;              // [128][40]
    unsigned short* Bs = smem + 128 * 40;   // [64][32] (gload16, XOR-swizzled)
    int wr = w >> 1, wc = w & 1;
    f32x4 acc[4][2] = {};
    for (int k0 = 0; k0 < 320; k0 += 32) {
#pragma unroll
      for (int i = 0; i < 4; ++i) {  // A: x f32 [128][32] -> bf16 [128][40]
        int u = tid + i * 256;
        int r = u >> 3, k4 = (u & 7) * 4;
        float4 t = *reinterpret_cast<const float4*>(p.x + (size_t)(mb128 + r) * 320 + k0 + k4);
        ushort4 o = {bf_cvt(t.x), bf_cvt(t.y), bf_cvt(t.z), bf_cvt(t.w)};
        *reinterpret_cast<ushort4*>(&As[r * 40 + k4]) = o;
      }
      { int r = w * 16 + (lane >> 2), cs = lane & 3;
        gload16(p.WqT + (size_t)(nb + r) * 320 + k0 + ((cs ^ (r & 3)) * 8), Bs + w * 512); }
      __syncthreads();
      bf16x8 a[4], b[2];
#pragma unroll
      for (int mi = 0; mi < 4; ++mi)
        a[mi] = *reinterpret_cast<const bf16x8*>(&As[(wr * 64 + mi * 16 + l15) * 40 + qd * 8]);
#pragma unroll
      for (int ni = 0; ni < 2; ++ni) {
        int row = wc * 32 + ni * 16 + l15;
        b[ni] = *reinterpret_cast<const bf16x8*>(&Bs[row * 32 + ((qd ^ (row & 3)) * 8)]);
      }
#pragma unroll
      for (int mi = 0; mi < 4; ++mi)
#pragma unroll
        for (int ni = 0; ni < 2; ++ni)
          acc[mi][ni] = mfma16(a[mi], b[ni], acc[mi][ni]);
      __syncthreads();
    }
#pragma unroll
    for (int mi = 0; mi < 4; ++mi)
#pragma unroll
      for (int ni = 0; ni < 2; ++ni)
#pragma unroll
        for (int r = 0; r < 4; ++r) {
          int m = mb128 + wr * 64 + mi * 16 + qd * 4 + r;
          int d = wc * 32 + ni * 16 + l15;
          int b_ = m >> 12, i = m & 4095;
          p.qb[((size_t)((b_ * 8 + nb_i) * 4096 + i)) * 64 + d] = bf_cvt(acc[mi][ni][r]);
        }
    if (mb >= 32) {  // q_c rows: compute this tile's sim_c0 max
      unsigned short* Qt = smem;  // [128][68] (reuse; all waves past last barrier)
#pragma unroll
      for (int mi = 0; mi < 4; ++mi)
#pragma unroll
        for (int ni = 0; ni < 2; ++ni)
#pragma unroll
          for (int r = 0; r < 4; ++r)
            Qt[(wr * 64 + mi * 16 + qd * 4 + r) * 68 + wc * 32 + ni * 16 + l15] =
                bf_cvt(acc[mi][ni][r]);
      __syncthreads();
      const unsigned short* kc = p.kb + (size_t)(1 * 8 + nb_i) * 80 * 64;  // c0
      float lmax = -3.4e38f;
#pragma unroll
      for (int mg = 0; mg < 2; ++mg) {
        int row = w * 32 + mg * 16 + l15;
        bf16x8 a0 = *reinterpret_cast<const bf16x8*>(&Qt[row * 68 + qd * 8]);
        bf16x8 a1 = *reinterpret_cast<const bf16x8*>(&Qt[row * 68 + qd * 8 + 32]);
#pragma unroll
        for (int jf = 0; jf < 5; ++jf) {
          bf16x8 b0 = *reinterpret_cast<const bf16x8*>(&kc[(size_t)(jf * 16 + l15) * 64 + qd * 8]);
          bf16x8 b1 = *reinterpret_cast<const bf16x8*>(&kc[(size_t)(jf * 16 + l15) * 64 + qd * 8 + 32]);
          f32x4 s = {};
          s = mfma16(a0, b0, s);
          s = mfma16(a1, b1, s);
          if (jf * 16 + l15 < 77) {
#pragma unroll
            for (int r = 0; r < 4; ++r) lmax = fmaxf(lmax, s[r]);
          }
        }
      }
      lmax *= 0.125f;
      for (int m = 1; m < 64; m <<= 1) lmax = fmaxf(lmax, __shfl_xor(lmax, m, 64));
      float* red = reinterpret_cast<float*>(smem_raw + 17408);
      if (lane == 0) red[w] = lmax;
      __syncthreads();
      if (tid == 0)
        atomicMax(p.maxslot, enc_f(fmaxf(fmaxf(red[0], red[1]), fmaxf(red[2], red[3]))));
    }
  }

  // ========== L2: fused attention (no K/V staging; Ps-only LDS) ============
  else if (ph == 2) {
    int rt = v / 40, rem = v % 40;
    int h = rem / 5, slot = rem % 5;
    int rowbase = rt * 64;
    int bh = slot ? 8 + h : h;
    unsigned short* Ps = smem;  // [64][104]
    for (int u = tid; u < 1024; u += 256) {  // zero pad cols 80..95
      int d = u >> 4, j = 80 + (u & 15);
      Ps[d * 104 + j] = 0;
    }
    __syncthreads();
    const unsigned short* kc = p.kb + (size_t)(slot * 8 + h) * 80 * 64;
    const unsigned short* vc = p.vtb + (size_t)(slot * 8 + h) * 64 * 96;
    int myrow = rowbase + w * 16 + l15;
    bf16x8 aq0 = *reinterpret_cast<const bf16x8*>(&p.qb[((size_t)bh * 4096 + myrow) * 64 + qd * 8]);
    bf16x8 aq1 = *reinterpret_cast<const bf16x8*>(&p.qb[((size_t)bh * 4096 + myrow) * 64 + qd * 8 + 32]);
    // QK^T from global (kb is L2-resident)
    f32x4 sim[5];
#pragma unroll
    for (int jf = 0; jf < 5; ++jf) {
      bf16x8 b0 = *reinterpret_cast<const bf16x8*>(&kc[(size_t)(jf * 16 + l15) * 64 + qd * 8]);
      bf16x8 b1 = *reinterpret_cast<const bf16x8*>(&kc[(size_t)(jf * 16 + l15) * 64 + qd * 8 + 32]);
      f32x4 s = {};
      s = mfma16(aq0, b0, s);
      s = mfma16(aq1, b1, s);
      sim[jf] = s;
    }
    const float weight = ((float)(*p.tp)) * (4.6f / 50.0f);
    float wmask_ = (slot == 1) ? weight * dec_f(*p.maxslot) : 0.f;
    int grow = rowbase + w * 16 + qd * 4;
    float rowsum[4] = {0.f, 0.f, 0.f, 0.f};
    float e[5][4];
#pragma unroll
    for (int jf = 0; jf < 5; ++jf) {
      int j = jf * 16 + l15;
#pragma unroll
      for (int r = 0; r < 4; ++r) {
        float ev = 0.f;
        if (j < 77) {
          float val = sim[jf][r] * 0.125f;
          if (slot == 1) val += wmask_ * p.ex[((size_t)h * 4096 + grow + r) * 77 + j];
          ev = __expf(val);
        }
        e[jf][r] = ev;
        rowsum[r] += ev;
      }
    }
#pragma unroll
    for (int r = 0; r < 4; ++r) {
      float s = rowsum[r];
      s += __shfl_xor(s, 1, 64); s += __shfl_xor(s, 2, 64);
      s += __shfl_xor(s, 4, 64); s += __shfl_xor(s, 8, 64);
      rowsum[r] = 1.0f / s;
    }
#pragma unroll
    for (int jf = 0; jf < 5; ++jf) {  // normalized P -> wave-private rows
      int j = jf * 16 + l15;
#pragma unroll
      for (int r = 0; r < 4; ++r)
        Ps[(w * 16 + qd * 4 + r) * 104 + j] = bf_cvt(e[jf][r] * rowsum[r]);
    }
    // PV: A from own Ps rows, B from global vtb (L2-resident, pitch 96, zero-padded)
    bf16x8 pa[3];
#pragma unroll
    for (int ks = 0; ks < 3; ++ks)
      pa[ks] = *reinterpret_cast<const bf16x8*>(&Ps[(w * 16 + l15) * 104 + qd * 8 + ks * 32]);
#pragma unroll
    for (int nf = 0; nf < 4; ++nf) {
      f32x4 o = {};
#pragma unroll
      for (int ks = 0; ks < 3; ++ks) {
        bf16x8 bv = *reinterpret_cast<const bf16x8*>(&vc[(size_t)(nf * 16 + l15) * 96 + qd * 8 + ks * 32]);
        o = mfma16(pa[ks], bv, o);
      }
      if (slot == 0) {
#pragma unroll
        for (int r = 0; r < 4; ++r)
          p.att0[((size_t)(grow + r)) * 512 + h * 64 + nf * 16 + l15] = bf_cvt(o[r]);
      } else {
#pragma unroll
        for (int r = 0; r < 4; ++r)
          p.attc[((size_t)((slot - 1) * 4096 + grow + r)) * 512 + h * 64 + nf * 16 + l15] = bf_cvt(o[r]);
      }
    }
  }

  // ==================== L3: out = att @ Wo + bo ===========================
  else {
    int mb = (v / 5) * 64, nb = (v % 5) * 64;
    bool ucpart = (mb < 4096);
    int mb2 = mb - 4096;
    unsigned short* As = smem;             // [64][40]
    unsigned short* Bs = smem + 64 * 40;   // [64][32]
    f32x4 acc[4] = {};
    for (int k0 = 0; k0 < 512; k0 += 32) {
      { int r = tid >> 2, cs = tid & 3;
        u16x8 val;
        if (ucpart) {
          val = *reinterpret_cast<const u16x8*>(&p.att0[(size_t)(mb + r) * 512 + k0 + cs * 8]);
        } else {
          float f[8] = {0.f, 0.f, 0.f, 0.f, 0.f, 0.f, 0.f, 0.f};
#pragma unroll
          for (int ci = 0; ci < 4; ++ci) {
            u16x8 t = *reinterpret_cast<const u16x8*>(
                &p.attc[((size_t)(ci * 4096 + mb2 + r)) * 512 + k0 + cs * 8]);
#pragma unroll
            for (int e2 = 0; e2 < 8; ++e2) f[e2] += bf2f((unsigned short)t[e2]);
          }
#pragma unroll
          for (int e2 = 0; e2 < 8; ++e2) val[e2] = bf_cvt(f[e2] * 0.25f);
        }
        *reinterpret_cast<u16x8*>(&As[r * 40 + cs * 8]) = val;
      }
      { int r = w * 16 + (lane >> 2), cs = lane & 3;
        gload16(p.WoT + (size_t)(nb + r) * 512 + k0 + ((cs ^ (r & 3)) * 8), Bs + w * 512); }
      __syncthreads();
      bf16x8 a = *reinterpret_cast<const bf16x8*>(&As[(w * 16 + l15) * 40 + qd * 8]);
#pragma unroll
      for (int nf = 0; nf < 4; ++nf) {
        int rb = nf * 16 + l15;
        bf16x8 b = *reinterpret_cast<const bf16x8*>(&Bs[rb * 32 + ((qd ^ (rb & 3)) * 8)]);
        acc[nf] = mfma16(a, b, acc[nf]);
      }
      __syncthreads();
    }
#pragma unroll
    for (int nf = 0; nf < 4; ++nf) {
      int n = nb + nf * 16 + l15;
      float bias = p.bo[n];
#pragma unroll
      for (int r = 0; r < 4; ++r)
        p.out[(size_t)(mb + w * 16 + qd * 4 + r) * 320 + n] = acc[nf][r] + bias;
    }
  }
}

extern "C" void kernel_launch(void* const* d_in, const int* in_sizes, int n_in,
                              void* d_out, int out_size, void* d_ws, size_t ws_size,
                              hipStream_t stream) {
  (void)in_sizes; (void)n_in; (void)out_size; (void)ws_size;
  char* base = (char*)d_ws;
  Params p;
  p.x  = (const float*)d_in[0];
  p.uc = (const float*)d_in[1];
  p.ck = (const float*)d_in[2];
  p.cv = (const float*)d_in[3];
  p.ex = (const float*)d_in[4];
  p.Wq = (const float*)d_in[5];
  p.Wk = (const float*)d_in[6];
  p.Wv = (const float*)d_in[7];
  p.Wo = (const float*)d_in[8];
  p.bo = (const float*)d_in[9];
  p.tp = (const int*)d_in[10];
  p.WqT  = (unsigned short*)(base + OFF_WQT);
  p.WoT  = (unsigned short*)(base + OFF_WOT);
  p.qb   = (unsigned short*)(base + OFF_QB);
  p.kb   = (unsigned short*)(base + OFF_KB);
  p.vtb  = (unsigned short*)(base + OFF_VTB);
  p.att0 = (unsigned short*)(base + OFF_ATT0);
  p.attc = (unsigned short*)(base + OFF_ATTC);
  p.maxslot = (unsigned*)(base + OFF_MAX);
  p.out = (float*)d_out;

  k_all<<<400,  256, 0, stream>>>(p, 0);  // WqT/WoT + ctx K/V GEMM
  k_all<<<512,  256, 0, stream>>>(p, 1);  // q-GEMM + folded sim_c0 max
  k_all<<<2560, 256, 0, stream>>>(p, 2);  // attention
  k_all<<<640,  256, 0, stream>>>(p, 3);  // out-GEMM
}